// Round 13
// baseline (1950.158 us; speedup 1.0000x reference)
//
#include <hip/hip_runtime.h>
#include <stdint.h>

typedef unsigned long long u64;

#define NB   32
#define TST  384
#define IDM  64
#define HDM  128
#define NCLS 10
#define EPSF 1e-7f
#define LOG2E 1.44269504088896340736f

// LDS layout (float offsets)
#define O_SBUF 0      // 388 (385 used) cached s_buf[t']
#define O_WLDS 388    // 388 attention weights w[t'] (LDS, NOT shfl: exec-mask safe)
#define O_DELT 776    // 32  deltas from all batches
#define O_MISC 808    // 16: [0]=s_h, [8..16)=wsp per wave
#define O_HC   824    // 128: cell output (w0 writes, all waves read)
#define O_ACT  952    // 64:  x_t only (h lives in registers)
#define O_GEX  1016   // 256: FC feature [h | attn]
#define O_GEXC 1272   // 512: gate exchange
#define O_RED  1784   // 768: gather partials 6x128
#define O_IDX  2552   // 384 ints: per-wave compacted positions
#define O_WFC  2936   // 10*264 = 2640 padded W_fc
#define O_BFC  5576   // 12
#define SMTOT  5588

__device__ __forceinline__ float sigm(float x) {
  return 1.0f / (1.0f + __builtin_amdgcn_exp2f(-LOG2E * x));
}
__device__ __forceinline__ float tanh_f(float x) {
  return 1.0f - 2.0f / (1.0f + __builtin_amdgcn_exp2f(2.0f * LOG2E * x));
}

// full-rate DPP add (VALU pipe)
template <int CTRL>
__device__ __forceinline__ float dppadd(float v) {
  int t = __builtin_amdgcn_update_dpp(0, __builtin_bit_cast(int, v), CTRL, 0xF, 0xF, true);
  return v + __builtin_bit_cast(float, t);
}
__device__ __forceinline__ float sum8(float v) {
  v = dppadd<0xB1>(v);   // quad_perm xor1
  v = dppadd<0x4E>(v);   // quad_perm xor2
  v = dppadd<0x141>(v);  // row_half_mirror (xor4)
  return v;
}
__device__ __forceinline__ float sum16(float v) {
  v = dppadd<0xB1>(v);
  v = dppadd<0x4E>(v);
  v = dppadd<0x141>(v);
  v = dppadd<0x140>(v);  // row_mirror (xor8)
  return v;
}
__device__ __forceinline__ float wave_sum(float v) {
  v = sum16(v);
  v += __shfl_xor(v, 16, 64);
  v += __shfl_xor(v, 32, 64);
  return v;
}

// System-scope (sc0 sc1) 8B mailbox ops: bypass L1/L2, meet at the memory-side
// Infinity Cache; no cache-invalidate side effects. Monolithic load+waitcnt.
__device__ __forceinline__ void mail_store(u64* p, u64 v) {
  asm volatile("global_store_dwordx2 %0, %1, off sc0 sc1"
               :: "v"(p), "v"(v) : "memory");
}
__device__ __forceinline__ u64 mail_load(u64* p) {
  u64 v;
  asm volatile("global_load_dwordx2 %0, %1, off sc0 sc1\n\t"
               "s_waitcnt vmcnt(0)"
               : "=v"(v) : "v"(p) : "memory");
  return v;
}

__global__ __launch_bounds__(512, 1)   // 256-VGPR budget (watch WRITE_SIZE for spill)
void sab_kernel(const float* __restrict__ x, const float* __restrict__ Wih,
                const float* __restrict__ Whh, const float* __restrict__ bihp,
                const float* __restrict__ bhhp, const float* __restrict__ wtp,
                const float* __restrict__ Wfcp, const float* __restrict__ bfcp,
                float* __restrict__ dout, u64* __restrict__ mail) {
  __shared__ __align__(16) float SM[SMTOT];
  int* IDX = (int*)(SM + O_IDX);

  const int tid  = threadIdx.x;
  const int lane = tid & 63;
  const int wvid = tid >> 6;
  const int b    = blockIdx.x;
  const int go   = tid >> 3;          // gate octet 0..63
  const int kc   = tid & 7;           // K-chunk: 8 x-cols + 16 h-cols

  float* hsout = dout + (size_t)NB * TST * NCLS;     // hs region == attention buf
  const float* myx = x + (size_t)b * TST * IDM;

  // ---- weights: rows 8*go..+7; x cols [8kc,8kc+8), h cols [16kc,16kc+16) ----
  float w[8][24];
  #pragma unroll
  for (int i = 0; i < 8; ++i) {
    const int g = 8 * go + i;
    #pragma unroll
    for (int j = 0; j < 8; ++j)  w[i][j]     = Wih[g * IDM + 8 * kc + j];
    #pragma unroll
    for (int j = 0; j < 16; ++j) w[i][8 + j] = Whh[g * HDM + 16 * kc + j];
  }
  const float bias = bihp[tid] + bhhp[tid];

  // wave-0-only scoring weights (dims 2*lane, 2*lane+1)
  float wt0a = 0.f, wt0b = 0.f, wt1a = 0.f, wt1b = 0.f;
  if (wvid == 0) {
    const float2 w0 = reinterpret_cast<const float2*>(wtp)[lane];
    const float2 w1 = reinterpret_cast<const float2*>(wtp + HDM)[lane];
    wt0a = w0.x; wt0b = w0.y; wt1a = w1.x; wt1b = w1.y;
  }
  float cst0 = 0.f, cst1 = 0.f;        // cell state (wave 0 only meaningful)
  float hv0 = 0.f, hv1 = 0.f;          // h(t) registers on ALL waves (dims 2lane,2lane+1)

  // top-5 of s_buf, uniform across wave 0; s_buf[0]=0 pre-inserted
  float t5a = 0.f, t5b = -3e38f, t5c = -3e38f, t5d = -3e38f, t5e = -3e38f;

  // ---- init LDS ----
  for (int idx = tid; idx < NCLS * 256; idx += 512)
    SM[O_WFC + (idx >> 8) * 264 + (idx & 255)] = Wfcp[idx];
  if (tid < NCLS) SM[O_BFC + tid] = bfcp[tid];
  if (tid < IDM) SM[O_ACT + tid] = myx[tid];   // x_0
  if (tid == 0) {
    SM[O_SBUF] = 0.f;
    mail_store(&mail[b], 0ull);
    mail_store(&mail[NB + b], 0ull);
  }
  __syncthreads();

  // pre-loop: x-part of gates for t=0
  float accx[8];
  {
    const float4* a4 = reinterpret_cast<const float4*>(SM + O_ACT + 8 * kc);
    const float4 av0 = a4[0], av1 = a4[1];
    #pragma unroll
    for (int i = 0; i < 8; ++i) {
      float a = 0.f;
      a = fmaf(av0.x, w[i][0], a); a = fmaf(av0.y, w[i][1], a);
      a = fmaf(av0.z, w[i][2], a); a = fmaf(av0.w, w[i][3], a);
      a = fmaf(av1.x, w[i][4], a); a = fmaf(av1.y, w[i][5], a);
      a = fmaf(av1.z, w[i][6], a); a = fmaf(av1.w, w[i][7], a);
      accx[i] = a;
    }
  }

  for (int t = 0; t < TST; ++t) {
    const int r = t + 1;
    const bool big = (r > 5);

    // ===== gates: h-part from REGISTERS (uniform shfl) + precomputed x-part ====
    float acc[8];
    #pragma unroll
    for (int i = 0; i < 8; ++i) acc[i] = accx[i];
    #pragma unroll
    for (int c = 0; c < 8; ++c) {          // h dims 16kc+2c, 16kc+2c+1
      const int src = 8 * kc + c;          // lane holding that dim pair
      const float h0 = __shfl(hv0, src, 64);   // uniform control flow: safe
      const float h1 = __shfl(hv1, src, 64);
      #pragma unroll
      for (int i = 0; i < 8; ++i) {
        acc[i] = fmaf(h0, w[i][8 + 2 * c], acc[i]);
        acc[i] = fmaf(h1, w[i][9 + 2 * c], acc[i]);
      }
    }
    #pragma unroll
    for (int i = 0; i < 8; ++i) acc[i] = sum8(acc[i]);   // octet butterfly (VALU)
    float pre = acc[0];
    #pragma unroll
    for (int i = 1; i < 8; ++i) if (kc == i) pre = acc[i];  // this thread's gate
    pre += bias;
    const bool tg = (tid >= 256) && (tid < 384);            // gg gates -> tanh
    SM[O_GEXC + tid] = tg ? tanh_f(pre) : sigm(pre);
    __syncthreads();                                        // B1

    // ===== window: cell+publish (w0) | poll (w7) | x (w6) | FC t-1 (w2-4) ======
    if (wvid == 0) {
      const float2 gi  = *reinterpret_cast<const float2*>(SM + O_GEXC + 2 * lane);
      const float2 gf  = *reinterpret_cast<const float2*>(SM + O_GEXC + 128 + 2 * lane);
      const float2 gg2 = *reinterpret_cast<const float2*>(SM + O_GEXC + 256 + 2 * lane);
      const float2 go2 = *reinterpret_cast<const float2*>(SM + O_GEXC + 384 + 2 * lane);
      cst0 = gf.x * cst0 + gi.x * gg2.x;
      cst1 = gf.y * cst1 + gi.y * gg2.y;
      const float hc0 = go2.x * tanh_f(cst0);
      const float hc1 = go2.y * tanh_f(cst1);
      *reinterpret_cast<float2*>(SM + O_HC + 2 * lane) = make_float2(hc0, hc1);
      const float sh = wave_sum(tanh_f(hc0) * wt0a + tanh_f(hc1) * wt0b);
      if (lane == 0) {
        SM[O_MISC] = sh;
        if (big) {
          const u64 pv = (((u64)(unsigned)r) << 32) | (u64)__float_as_uint(t5e + sh + EPSF);
          mail_store(&mail[(r & 1) * NB + b], pv);
        }
      }
    } else if (wvid == 7) {
      if (big && lane < NB) {
        u64* slot = &mail[(r & 1) * NB + lane];
        u64 v = mail_load(slot);
        while ((unsigned)(v >> 32) != (unsigned)r) v = mail_load(slot);
        SM[O_DELT + lane] = __uint_as_float((unsigned)v);
      }
    } else if (wvid == 6) {
      if (t + 1 < TST && lane < IDM)
        SM[O_ACT + lane] = myx[(size_t)(t + 1) * IDM + lane];
    } else if (t > 0 && tid >= 128 && tid < 288) {   // waves 2-4: FC for step t-1
      const int cls = (tid - 128) >> 4, p = tid & 15;
      float pt = 0.f;
      #pragma unroll
      for (int i = 0; i < 16; ++i) {
        const int k = p + 16 * i;
        pt = fmaf(SM[O_WFC + cls * 264 + k], SM[O_GEX + k], pt);
      }
      pt = sum16(pt);
      if (p == 0) dout[((size_t)(b * TST + (t - 1))) * NCLS + cls] = pt + SM[O_BFC + cls];
    }
    __syncthreads();                                        // B2

    // ===== scores + own-wave compaction + gather; acc_x(t+1) as filler =========
    const float s_h = SM[O_MISC];
    float wval = 0.f;
    bool pred = false;
    if (big) {
      if (tid < r) {
        const float sc = s_h + SM[O_SBUF + tid];
        wval = fmaxf(sc - SM[O_DELT + ((b * r + tid) & (NB - 1))], 0.f);
        pred = (wval > 0.f) && (tid > 0);   // t'=0 row is zeros
      }
    } else {
      float scv = (tid < r) ? (s_h + SM[O_SBUF + tid]) : -3e38f;
      float mx = scv;
      mx = fmaxf(mx, __shfl_xor(mx, 1, 64));  mx = fmaxf(mx, __shfl_xor(mx, 2, 64));
      mx = fmaxf(mx, __shfl_xor(mx, 4, 64));  mx = fmaxf(mx, __shfl_xor(mx, 8, 64));
      mx = fmaxf(mx, __shfl_xor(mx, 16, 64)); mx = fmaxf(mx, __shfl_xor(mx, 32, 64));
      if (tid < r) {
        wval = __builtin_amdgcn_exp2f(LOG2E * (scv - mx));
        pred = (tid > 0);
      }
    }
    if (tid < r) SM[O_WLDS + tid] = wval;    // guarded store (388-float region)
    const float wsp = wave_sum(wval);
    if (lane == 0) SM[O_MISC + 8 + wvid] = wsp;
    const u64 bmask = __ballot((int)pred);
    const int cnt = (int)__popcll(bmask);
    if (pred) {                              // pred => tid<r<=384 => wvid<6
      const int pos = (int)__popcll(bmask & ((1ull << lane) - 1ull));
      IDX[(wvid << 6) + pos] = tid;
    }
    // gather: 4 sub-groups x 16 lanes take ranks sub+4k of OWN wave's list;
    // weight read from LDS (WLDS) — ds ops are exec-mask safe in divergent loops
    // (R12's __shfl here read from exec-inactive lanes -> garbage)
    if (wvid < 6) {
      const int sub = lane >> 4;
      const int j8 = lane & 15;
      float ac0=0.f,ac1=0.f,ac2=0.f,ac3=0.f,ac4=0.f,ac5=0.f,ac6=0.f,ac7=0.f;
      for (int rk = sub; rk < cnt; rk += 4) {
        const int tp = IDX[(wvid << 6) + rk];
        const float wgt = SM[O_WLDS + tp];
        const float* bp = hsout + ((size_t)(b * TST + tp - 1)) * HDM + j8 * 8;
        const float4 v0 = *reinterpret_cast<const float4*>(bp);
        const float4 v1 = *reinterpret_cast<const float4*>(bp + 4);
        ac0 = fmaf(wgt, v0.x, ac0); ac1 = fmaf(wgt, v0.y, ac1);
        ac2 = fmaf(wgt, v0.z, ac2); ac3 = fmaf(wgt, v0.w, ac3);
        ac4 = fmaf(wgt, v1.x, ac4); ac5 = fmaf(wgt, v1.y, ac5);
        ac6 = fmaf(wgt, v1.z, ac6); ac7 = fmaf(wgt, v1.w, ac7);
      }
      ac0 += __shfl_xor(ac0,16,64); ac0 += __shfl_xor(ac0,32,64);
      ac1 += __shfl_xor(ac1,16,64); ac1 += __shfl_xor(ac1,32,64);
      ac2 += __shfl_xor(ac2,16,64); ac2 += __shfl_xor(ac2,32,64);
      ac3 += __shfl_xor(ac3,16,64); ac3 += __shfl_xor(ac3,32,64);
      ac4 += __shfl_xor(ac4,16,64); ac4 += __shfl_xor(ac4,32,64);
      ac5 += __shfl_xor(ac5,16,64); ac5 += __shfl_xor(ac5,32,64);
      ac6 += __shfl_xor(ac6,16,64); ac6 += __shfl_xor(ac6,32,64);
      ac7 += __shfl_xor(ac7,16,64); ac7 += __shfl_xor(ac7,32,64);
      if (sub == 0) {
        float4* r4 = reinterpret_cast<float4*>(SM + O_RED + wvid * 128 + j8 * 8);
        r4[0] = make_float4(ac0, ac1, ac2, ac3);
        r4[1] = make_float4(ac4, ac5, ac6, ac7);
      }
    }
    // x-part of gates for t+1 (x_{t+1} in ACT since the window; filler work)
    {
      const float4* a4 = reinterpret_cast<const float4*>(SM + O_ACT + 8 * kc);
      const float4 av0 = a4[0], av1 = a4[1];
      #pragma unroll
      for (int i = 0; i < 8; ++i) {
        float a = 0.f;
        a = fmaf(av0.x, w[i][0], a); a = fmaf(av0.y, w[i][1], a);
        a = fmaf(av0.z, w[i][2], a); a = fmaf(av0.w, w[i][3], a);
        a = fmaf(av1.x, w[i][4], a); a = fmaf(av1.y, w[i][5], a);
        a = fmaf(av1.z, w[i][6], a); a = fmaf(av1.w, w[i][7], a);
        accx[i] = a;
      }
    }
    __syncthreads();                                        // B3

    // ===== finalize on ALL waves: h(t) stays in registers ======================
    {
      float wsum = 0.f;
      #pragma unroll
      for (int i = 0; i < 8; ++i) wsum += SM[O_MISC + 8 + i];
      const float inv = 1.0f / (wsum + (big ? EPSF : 0.0f));
      const float2 hcv = *reinterpret_cast<const float2*>(SM + O_HC + 2 * lane);
      float s0 = 0.f, s1 = 0.f;
      #pragma unroll
      for (int wv2 = 0; wv2 < 6; ++wv2) {
        const float2 p2 = reinterpret_cast<const float2*>(SM + O_RED + wv2 * 128)[lane];
        s0 += p2.x; s1 += p2.y;
      }
      const float at0 = s0 * inv, at1 = s1 * inv;
      hv0 = hcv.x + at0;
      hv1 = hcv.y + at1;
      if (wvid == 0) {
        reinterpret_cast<float2*>(hsout + (size_t)(b * TST + t) * HDM)[lane] =
            make_float2(hv0, hv1);
        reinterpret_cast<float2*>(SM + O_GEX)[lane] = make_float2(hv0, hv1);
        reinterpret_cast<float2*>(SM + O_GEX + 128)[lane] = make_float2(at0, at1);
        if (r < TST) {
          const float tb = wave_sum(tanh_f(hv0) * wt1a + tanh_f(hv1) * wt1b);
          if (lane == 0) SM[O_SBUF + r] = tb;
          if (tb > t5e) {              // uniform insert across wave 0
            if (tb > t5a)      { t5e=t5d; t5d=t5c; t5c=t5b; t5b=t5a; t5a=tb; }
            else if (tb > t5b) { t5e=t5d; t5d=t5c; t5c=t5b; t5b=tb; }
            else if (tb > t5c) { t5e=t5d; t5d=t5c; t5c=tb; }
            else if (tb > t5d) { t5e=t5d; t5d=tb; }
            else               { t5e=tb; }
          }
        }
      }
    }
    // no loop-end barrier needed: finalize reads (RED/HC/MISC) are only
    // re-written after the NEXT B1/B2; GEXC writes don't overlap them.
  }

  __syncthreads();
  // final FC for t = 383
  if (tid < 160) {
    const int cls = tid >> 4, p = tid & 15;
    float pt = 0.f;
    #pragma unroll
    for (int i = 0; i < 16; ++i) {
      const int k = p + 16 * i;
      pt = fmaf(SM[O_WFC + cls * 264 + k], SM[O_GEX + k], pt);
    }
    pt = sum16(pt);
    if (p == 0) dout[((size_t)(b * TST + (TST - 1))) * NCLS + cls] = pt + SM[O_BFC + cls];
  }
}

extern "C" void kernel_launch(void* const* d_in, const int* in_sizes, int n_in,
                              void* d_out, int out_size, void* d_ws, size_t ws_size,
                              hipStream_t stream) {
  const float* x   = (const float*)d_in[0];
  const float* Wih = (const float*)d_in[1];
  const float* Whh = (const float*)d_in[2];
  const float* bih = (const float*)d_in[3];
  const float* bhh = (const float*)d_in[4];
  const float* wt  = (const float*)d_in[5];
  const float* Wfc = (const float*)d_in[6];
  const float* bfc = (const float*)d_in[7];
  sab_kernel<<<dim3(NB), dim3(512), 0, stream>>>(
      x, Wih, Whh, bih, bhh, wt, Wfc, bfc, (float*)d_out, (u64*)d_ws);
}

// Round 14
// 1885.570 us; speedup vs baseline: 1.0343x; 1.0343x over previous
//
#include <hip/hip_runtime.h>
#include <stdint.h>

typedef unsigned long long u64;

#define NB   32
#define TST  384
#define IDM  64
#define HDM  128
#define NCLS 10
#define EPSF 1e-7f
#define LOG2E 1.44269504088896340736f

// LDS layout (float offsets) — round-1 layout; gate exchange moved to O_RED
#define O_SBUF 0      // 385 (pad->388)  cached s_buf[t']
#define O_WLDS 388    // 388             attention weights w[t']
#define O_ACT  776    // 192             [x_t(64) | h(128)] activations
#define O_GEX  968    // 512             FC feature [h|attn] in [0..256); IDX ints in [0..384)
#define O_RED  1480   // 1024            gate exchange (S1, [0..512)) + attn partials (S6, 8x128)
#define O_DELT 2504   // 32              deltas from all batches
#define O_WFC  2536   // 10*264 = 2640   padded W_fc
#define O_BFC  5176   // 12
#define O_MISC 5188   // 32
#define SMTOT  5220

__device__ __forceinline__ float sigm(float x) {
  return 1.0f / (1.0f + __builtin_amdgcn_exp2f(-LOG2E * x));
}
__device__ __forceinline__ float tanh_f(float x) {
  return 1.0f - 2.0f / (1.0f + __builtin_amdgcn_exp2f(2.0f * LOG2E * x));
}

// System-scope (sc0 sc1) 8B mailbox ops: bypass L1/L2, meet at the memory-side
// Infinity Cache. No buffer_inv / wbl2 side effects (the agent-scope
// acquire/release poll was invalidating the whole XCD L2 every iteration).
__device__ __forceinline__ void mail_store(u64* p, u64 v) {
  asm volatile("global_store_dwordx2 %0, %1, off sc0 sc1"
               :: "v"(p), "v"(v) : "memory");
}
__device__ __forceinline__ u64 mail_load(u64* p) {
  u64 v;
  asm volatile("global_load_dwordx2 %0, %1, off sc0 sc1\n\t"
               "s_waitcnt vmcnt(0)"
               : "=v"(v) : "v"(p) : "memory");
  return v;
}

__global__ __launch_bounds__(512, 2)
void sab_kernel(const float* __restrict__ x, const float* __restrict__ Wih,
                const float* __restrict__ Whh, const float* __restrict__ bihp,
                const float* __restrict__ bhhp, const float* __restrict__ wtp,
                const float* __restrict__ Wfcp, const float* __restrict__ bfcp,
                float* __restrict__ dout, u64* __restrict__ mail) {
  __shared__ __align__(16) float SM[SMTOT];
  int* IMISC = (int*)(SM + O_MISC);   // ints at slots 16..23 (counts)
  int* IDX   = (int*)(SM + O_GEX);    // compacted t' indices (reuses GEX)

  const int tid  = threadIdx.x;
  const int lane = tid & 63;
  const int wvid = tid >> 6;
  const int b    = blockIdx.x;
  const int go   = tid >> 3;          // gate octet 0..63
  const int kc   = tid & 7;           // K-chunk 0..7 (24 cols each)

  float* hsout = dout + (size_t)NB * TST * NCLS;     // hs region == attention buf
  const float* myx = x + (size_t)b * TST * IDM;

  // ---- preload weight sub-block: rows 8*go..8*go+7, cols 24*kc..24*kc+23 ----
  float w[8][24];
  #pragma unroll
  for (int i = 0; i < 8; ++i) {
    const int g = 8 * go + i;
    #pragma unroll
    for (int j = 0; j < 24; ++j) {
      const int k = 24 * kc + j;
      const float* sp = (k < IDM) ? (Wih + g * IDM + k) : (Whh + g * HDM + (k - IDM));
      w[i][j] = *sp;
    }
  }
  const float bias = bihp[tid] + bhhp[tid];
  float wt0 = 0.f, wt1 = 0.f, cst = 0.f;
  if (tid < HDM) { wt0 = wtp[tid]; wt1 = wtp[HDM + tid]; }

  // incremental top-5 of s_buf (thread 0 only meaningful); s_buf[0]=0 pre-inserted
  float t5a = 0.f, t5b = -3e38f, t5c = -3e38f, t5d = -3e38f, t5e = -3e38f;

  // ---- init LDS ----
  for (int idx = tid; idx < NCLS * 256; idx += 512) {
    const int c = idx >> 8, k = idx & 255;
    SM[O_WFC + c * 264 + k] = Wfcp[idx];
  }
  if (tid < NCLS) SM[O_BFC + tid] = bfcp[tid];
  if (tid < HDM) SM[O_ACT + 64 + tid] = 0.f;   // h0 = 0
  if (tid < IDM) SM[O_ACT + tid] = myx[tid];   // x_0
  if (tid == 0) {
    SM[O_SBUF] = 0.f;
    mail_store(&mail[b], 0ull);
    mail_store(&mail[NB + b], 0ull);
  }
  __syncthreads();

  float hc = 0.f;
  for (int t = 0; t < TST; ++t) {
    const int r = t + 1;
    const bool big = (r > 5);

    // ================= gates: g = [x|h] @ W^T + bias =================
    float acc[8] = {0,0,0,0,0,0,0,0};
    {
      const float4* a4 = reinterpret_cast<const float4*>(SM + O_ACT + kc * 24);
      #pragma unroll
      for (int m = 0; m < 6; ++m) {
        const float4 av = a4[m];
        #pragma unroll
        for (int i = 0; i < 8; ++i) {
          acc[i] = fmaf(av.x, w[i][4*m+0], acc[i]);
          acc[i] = fmaf(av.y, w[i][4*m+1], acc[i]);
          acc[i] = fmaf(av.z, w[i][4*m+2], acc[i]);
          acc[i] = fmaf(av.w, w[i][4*m+3], acc[i]);
        }
      }
    }
    #pragma unroll
    for (int i = 0; i < 8; ++i) {   // butterfly over the 8 kc lanes
      acc[i] += __shfl_xor(acc[i], 1, 64);
      acc[i] += __shfl_xor(acc[i], 2, 64);
      acc[i] += __shfl_xor(acc[i], 4, 64);
    }
    float pre = acc[0];
    #pragma unroll
    for (int i = 1; i < 8; ++i) if (kc == i) pre = acc[i];  // this thread's gate = tid
    pre += bias;
    const bool tg = (tid >= 256) && (tid < 384);            // gg gates -> tanh
    SM[O_RED + tid] = tg ? tanh_f(pre) : sigm(pre);         // gate exchange in RED
    __syncthreads();                                        // S1

    // ================= LSTM cell (threads 0..127) =================
    float th = 0.f;
    if (tid < HDM) {
      const float iv = SM[O_RED + tid];
      const float fv = SM[O_RED + 128 + tid];
      const float gv = SM[O_RED + 256 + tid];
      const float ov = SM[O_RED + 384 + tid];
      cst = fv * cst + iv * gv;
      hc  = ov * tanh_f(cst);
      th  = tanh_f(hc) * wt0;        // partial of s_h
    }
    #pragma unroll
    for (int s = 1; s < 64; s <<= 1) th += __shfl_xor(th, s, 64);
    if (lane == 0 && tid < HDM) SM[O_MISC + wvid] = th;
    __syncthreads();                                        // S2
    const float s_h = SM[O_MISC] + SM[O_MISC + 1];

    // ---- publish delta (tid0, sc0sc1 write-through) ----
    if (big && tid == 0) {
      const float delta = t5e + s_h + EPSF;                 // 5th-largest score + eps
      const u64 pv = (((u64)(unsigned)r) << 32) | (u64)__float_as_uint(delta);
      mail_store(&mail[(r & 1) * NB + b], pv);
    }

    // ---- overlapped with the exchange flight: x-prefetch + FC(t-1) ----
    float xr = 0.f;
    if (tid < IDM && t + 1 < TST) xr = myx[(size_t)(t + 1) * IDM + tid];
    if (t > 0 && tid < 160) {       // reads GEX written at finalize of step t-1
      const int cls = tid >> 4, p = tid & 15;
      float pt = 0.f;
      #pragma unroll
      for (int i = 0; i < 16; ++i) {
        const int k = p + 16 * i;
        pt = fmaf(SM[O_WFC + cls * 264 + k], SM[O_GEX + k], pt);
      }
      #pragma unroll
      for (int s2 = 1; s2 < 16; s2 <<= 1) pt += __shfl_xor(pt, s2, 64);
      if (p == 0) dout[((size_t)(b * TST + (t - 1))) * NCLS + cls] = pt + SM[O_BFC + cls];
    }

    // ---- poll on wave 7 (sc0sc1 loads: no cache invalidation) ----
    if (big && wvid == 7 && lane < NB) {
      u64* slot = &mail[(r & 1) * NB + lane];
      u64 v = mail_load(slot);
      while ((unsigned)(v >> 32) != (unsigned)r) {
        __builtin_amdgcn_s_sleep(2);
        v = mail_load(slot);
      }
      SM[O_DELT + lane] = __uint_as_float((unsigned)v);
    }
    __syncthreads();                                        // S3

    // ================= attention weights =================
    float wval = 0.f;
    bool pred = false;
    if (big) {
      if (tid < r) {
        const float sc = s_h + SM[O_SBUF + tid];
        wval = fmaxf(sc - SM[O_DELT + ((b * r + tid) & (NB - 1))], 0.f);
        SM[O_WLDS + tid] = wval;
        pred = (wval > 0.f) && (tid > 0);   // t'=0 row is zeros: no contribution
      }
    } else {
      float scv = (tid < r) ? (s_h + SM[O_SBUF + tid]) : -3e38f;
      float mx = scv;
      #pragma unroll
      for (int s = 1; s < 64; s <<= 1) mx = fmaxf(mx, __shfl_xor(mx, s, 64));
      if (tid < r) {
        wval = __builtin_amdgcn_exp2f(LOG2E * (scv - mx));
        SM[O_WLDS + tid] = wval;
        pred = (tid > 0);
      }
    }
    float wsp = wval;
    #pragma unroll
    for (int s = 1; s < 64; s <<= 1) wsp += __shfl_xor(wsp, s, 64);
    if (lane == 0) SM[O_MISC + 2 + wvid] = wsp;
    const u64 bmask = __ballot((int)pred);
    if (lane == 0) IMISC[16 + wvid] = (int)__popcll(bmask);
    __syncthreads();                                        // S4

    float wsum = 0.f;
    #pragma unroll
    for (int i = 0; i < 8; ++i) wsum += SM[O_MISC + 2 + i];
    const float inv = 1.0f / (wsum + (big ? EPSF : 0.f));
    int wbase = 0, nnz = 0;
    #pragma unroll
    for (int i = 0; i < 8; ++i) {
      const int c = IMISC[16 + i];
      if (i < wvid) wbase += c;
      nnz += c;
    }
    if (pred) {
      const int pos = wbase + (int)__popcll(bmask & ((1ull << lane) - 1ull));
      IDX[pos] = tid;
    }
    __syncthreads();                                        // S5

    // ================= attn_c: sparse gather over buf (== hs rows) =================
    const int j8 = tid & 15, q = tid >> 4;
    float ac[8] = {0,0,0,0,0,0,0,0};
    for (int ii = q; ii < nnz; ii += 32) {
      const int tp = IDX[ii];                                // t' index (>=1)
      const float wgt = SM[O_WLDS + tp] * inv;
      const float* bp = hsout + ((size_t)(b * TST + tp - 1)) * HDM + j8 * 8;
      const float4 v0 = *reinterpret_cast<const float4*>(bp);
      const float4 v1 = *reinterpret_cast<const float4*>(bp + 4);
      ac[0] = fmaf(wgt, v0.x, ac[0]); ac[1] = fmaf(wgt, v0.y, ac[1]);
      ac[2] = fmaf(wgt, v0.z, ac[2]); ac[3] = fmaf(wgt, v0.w, ac[3]);
      ac[4] = fmaf(wgt, v1.x, ac[4]); ac[5] = fmaf(wgt, v1.y, ac[5]);
      ac[6] = fmaf(wgt, v1.z, ac[6]); ac[7] = fmaf(wgt, v1.w, ac[7]);
    }
    #pragma unroll
    for (int i = 0; i < 8; ++i) {     // reduce the 4 q-groups inside each wave
      ac[i] += __shfl_xor(ac[i], 16, 64);
      ac[i] += __shfl_xor(ac[i], 32, 64);
    }
    if ((q & 3) == 0) {
      float4* r4 = reinterpret_cast<float4*>(SM + O_RED + wvid * 128 + j8 * 8);
      r4[0] = make_float4(ac[0], ac[1], ac[2], ac[3]);
      r4[1] = make_float4(ac[4], ac[5], ac[6], ac[7]);
    }
    __syncthreads();                                        // S6

    // ================= finalize h, write outputs =================
    float tb = 0.f;
    if (tid < HDM) {
      float s = 0.f;
      #pragma unroll
      for (int wv2 = 0; wv2 < 8; ++wv2) s += SM[O_RED + wv2 * 128 + tid];
      const float hf = hc + s;
      hsout[((size_t)(b * TST + t)) * HDM + tid] = hf;
      SM[O_ACT + 64 + tid] = hf;       // h for next step's gates
      SM[O_GEX + tid] = hf;            // FC input [h | attn_c]
      SM[O_GEX + 128 + tid] = s;
      tb = tanh_f(hf) * wt1;           // partial of s_buf[r]
    }
    if (tid < IDM && t + 1 < TST) SM[O_ACT + tid] = xr;
    #pragma unroll
    for (int s2 = 1; s2 < 64; s2 <<= 1) tb += __shfl_xor(tb, s2, 64);
    if (lane == 0 && tid < HDM) SM[O_MISC + 24 + wvid] = tb;
    __syncthreads();                                        // S7

    if (tid == 0 && r < TST) {
      const float sb = SM[O_MISC + 24] + SM[O_MISC + 25];
      SM[O_SBUF + r] = sb;
      if (sb > t5e) {                  // maintain 5 largest s_buf values
        if (sb > t5a)      { t5e=t5d; t5d=t5c; t5c=t5b; t5b=t5a; t5a=sb; }
        else if (sb > t5b) { t5e=t5d; t5d=t5c; t5c=t5b; t5b=sb; }
        else if (sb > t5c) { t5e=t5d; t5d=t5c; t5c=sb; }
        else if (sb > t5d) { t5e=t5d; t5d=sb; }
        else               { t5e=sb; }
      }
    }
  }

  // final FC for t = 383 (reads GEX written at last finalize)
  if (tid < 160) {
    const int cls = tid >> 4, p = tid & 15;
    float pt = 0.f;
    #pragma unroll
    for (int i = 0; i < 16; ++i) {
      const int k = p + 16 * i;
      pt = fmaf(SM[O_WFC + cls * 264 + k], SM[O_GEX + k], pt);
    }
    #pragma unroll
    for (int s2 = 1; s2 < 16; s2 <<= 1) pt += __shfl_xor(pt, s2, 64);
    if (p == 0) dout[((size_t)(b * TST + (TST - 1))) * NCLS + cls] = pt + SM[O_BFC + cls];
  }
}

extern "C" void kernel_launch(void* const* d_in, const int* in_sizes, int n_in,
                              void* d_out, int out_size, void* d_ws, size_t ws_size,
                              hipStream_t stream) {
  const float* x   = (const float*)d_in[0];
  const float* Wih = (const float*)d_in[1];
  const float* Whh = (const float*)d_in[2];
  const float* bih = (const float*)d_in[3];
  const float* bhh = (const float*)d_in[4];
  const float* wt  = (const float*)d_in[5];
  const float* Wfc = (const float*)d_in[6];
  const float* bfc = (const float*)d_in[7];
  sab_kernel<<<dim3(NB), dim3(512), 0, stream>>>(
      x, Wih, Whh, bih, bhh, wt, Wfc, bfc, (float*)d_out, (u64*)d_ws);
}